// Round 21
// baseline (52.825 us; speedup 1.0000x reference)
//
#include <hip/hip_runtime.h>
#include <math.h>

// HungarianLoss: B=4096 independent 32x32 degenerate-JV problems + matched loss.
// ONE PROBLEM PER 64-THREAD BLOCK this round (was 4 per 256-thread block).
// LDS is padded to ~13.3KB so only 12 blocks/CU are co-resident (3 waves/SIMD);
// the remaining 1024 blocks form a backlog the HW dispatcher assigns to
// whichever CU frees first -> greedy load balancing of the step-count tail
// (r20 counters: VALUBusy 62%, Occupancy 23% vs 50% static = ~1.5x tail).
// Walk code byte-identical to r20 (passed absmax 0.0).
//
// Reference semantics (its _lsa_square never writes back minv/way):
//   for row i: j0=0; used={}; p[0]=i
//     loop: used+={j0}; i0=p[j0]
//           j1 = argmin_{free j}(cost[i0-1][j] - u[i0] - v[j]); delta = that min
//           u[p[used]] += delta; v[used] -= delta
//           j0=j1; if p[j0]==0 break
//     p[j0] = i   // only terminal column assigned

constexpr int BB = 4096;
constexpr int NN = 32;
constexpr int TT = 8;
constexpr float ALPHA_F = 1.0f;
constexpr float BETA_F  = 0.5f;
constexpr float EPS_F   = 1e-8f;

typedef float f32x32 __attribute__((ext_vector_type(32)));

template <int CTRL, int ROW_MASK>
__device__ __forceinline__ float dpp_min(float x) {
    int t = __builtin_amdgcn_update_dpp(__float_as_int(x), __float_as_int(x),
                                        CTRL, ROW_MASK, 0xf, false);
    return fminf(x, __int_as_float(t));
}

// Min over lanes 0-31; broadcast via readlane (ignores EXEC). Bit-exact r6-r20.
__device__ __forceinline__ float wave32_min_bcast(float x) {
    x = dpp_min<0xB1,  0xf>(x); // quad_perm [1,0,3,2]  (xor 1)
    x = dpp_min<0x4E,  0xf>(x); // quad_perm [2,3,0,1]  (xor 2)
    x = dpp_min<0x124, 0xf>(x); // row_ror:4
    x = dpp_min<0x128, 0xf>(x); // row_ror:8   -> per-16-row min
    x = dpp_min<0x142, 0xa>(x); // row_bcast15 -> row 1 has 32-min
    return __int_as_float(__builtin_amdgcn_readlane(__float_as_int(x), 31));
}

__device__ __forceinline__ float readlane_f(float x, int lane) {
    return __int_as_float(__builtin_amdgcn_readlane(__float_as_int(x), lane));
}

__global__ __launch_bounds__(64) void hungarian_lsa_kernel(
    const float* __restrict__ pred_j,
    const float* __restrict__ logits,
    const float* __restrict__ target_j,
    const int*   __restrict__ target_types,
    double* __restrict__ partials)
{
    __shared__ float lgp[NN * TT];       // log(softmax+eps), 1 KB
    __shared__ float lgt[NN * TT];       // raw logits for epilogue gather
    __shared__ char  padS[11264];        // residency throttle: ~13.3KB/block
                                         // -> 12 blocks/CU, 1024-block backlog

    const int lane = threadIdx.x & 63;
    const int col  = lane & 31;
    const int b    = blockIdx.x;

    if (pred_j == nullptr) ((volatile char*)padS)[0] = 1;   // keep padS alive

    // ---- per-lane row data (lane r <-> row r) ----
    const float pj = pred_j  [b * NN + col];
    const float tj = target_j[b * NN + col];
    const int   tt = target_types[b * NN + col];

    float x[TT];
    const float* lrow = logits + ((size_t)b * NN + col) * TT;
#pragma unroll
    for (int t = 0; t < TT; ++t) x[t] = lrow[t];

    float m = x[0]; int am = 0;
#pragma unroll
    for (int t = 1; t < TT; ++t) { if (x[t] > m) { m = x[t]; am = t; } }
    float s = 0.f;
#pragma unroll
    for (int t = 0; t < TT; ++t) s += expf(x[t] - m);
    const float lse = m + logf(s);

    if (lane < 32) {
#pragma unroll
        for (int t = 0; t < TT; ++t) {
            float p = expf(x[t] - m) / s;
            lgp[col * TT + t] = logf(p + EPS_F);
            lgt[col * TT + t] = x[t];
        }
    }
    __syncthreads();

    int p_m1 = 0;        // 0-based row assigned to this col
    if (lane < 32) {     // EXEC upper half = 0 for the entire hot section
        // ---- cost column in a 32-wide register vector: cc[r] = cost[r][col] ----
        f32x32 cc;
#pragma unroll
        for (int r = 0; r < NN; ++r) {
            const float pjr = readlane_f(pj, r);       // row r's pred_j (uniform)
            const float lp  = lgp[r * TT + tt];        // LDS gather, pipelined
            cc[r] = ALPHA_F * fabsf(pjr - tj) + BETA_F * (-lp);
        }

        // ---- degenerate shortest-path walks (r20's proven loop, unchanged) ----
        const float INFF = __builtin_inff();
        float negv = 0.f;    // -v[col+1]  (frozen during a walk)
        float ucf  = 0.f;    // u[p[col+1]] (frozen during a walk)
        unsigned amask = 0u; // assigned-column bitmask (wave-uniform)

        for (int i = 1; i <= NN; ++i) {
            float nvm   = negv;  // per-lane: -v, overwritten with INF at join
            float snap  = 0.f;   // rowSum at the moment col joined
            float curm  = cc[i - 1] + nvm;
            float mv    = wave32_min_bcast(curm);
            unsigned long long bm = __ballot(curm == mv);
            int   j1m1  = __ffsll(bm) - 1;     // argmin col (lowest on ties)
            float rowSum = mv;                 // u[i] accumulator (uniform value)

            while ((amask >> j1m1) & 1u) {     // chosen col assigned -> walk on
                const bool isJ = (col == j1m1);
                snap = isJ ? rowSum : snap;    // join: window starts here
                nvm  = isJ ? INFF   : nvm;     // join: exclude from argmin
                const float u_curV = readlane_f(ucf, j1m1);        // walk-start u
                const int   r0     = __builtin_amdgcn_readlane(p_m1, j1m1);
                curm = cc[r0] + nvm;                               // uniform idx
                mv   = wave32_min_bcast(curm);
                bm   = __ballot(curm == mv);
                j1m1 = __ffsll(bm) - 1;
                rowSum += mv - u_curV;
            }

            // terminal: assign row i to column j1; apply deferred duals
            const bool isJ = (col == j1m1);
            p_m1 = isJ ? (i - 1) : p_m1;
            const float dv  = rowSum - snap;             // deltas since join
            const float dvj = (nvm == INFF) ? dv : 0.f;  // joined lanes only
            negv += dvj;                                 // v[used] -= dv
            ucf  += dvj;                                 // u[p[used]] += dv
            ucf   = isJ ? rowSum : ucf;                  // u[i] -> terminal col
            amask |= 1u << j1m1;
        }
    }

    // ---- matched loss contributions (column-centric; bijection == row sum) ----
    const int   row      = p_m1;                 // upper lanes: 0 (masked below)
    const float pj_row   = __shfl(pj,  row);
    const float lse_row  = __shfl(lse, row);
    const int   am_row   = __shfl(am,  row);
    const float logit_tt = lgt[row * TT + tt];

    double sj = (lane < 32) ? (double)fabsf(pj_row - tj)   : 0.0;
    double st = (lane < 32) ? (double)(lse_row - logit_tt) : 0.0;
    double sa = (lane < 32) ? ((am_row == tt) ? 1.0 : 0.0) : 0.0;
#pragma unroll
    for (int off = 32; off >= 1; off >>= 1) {
        sj += __shfl_xor(sj, off);
        st += __shfl_xor(st, off);
        sa += __shfl_xor(sa, off);
    }
    if (lane == 0) {
        partials[b * 3 + 0] = sj;
        partials[b * 3 + 1] = st;
        partials[b * 3 + 2] = sa;
    }
}

__global__ __launch_bounds__(256) void hungarian_finalize_kernel(
    const double* __restrict__ partials, float* __restrict__ out)
{
    __shared__ double sm0[256], sm1[256], sm2[256];
    const int tid = threadIdx.x;
    double a = 0.0, c = 0.0, e = 0.0;
    for (int i = tid; i < BB; i += 256) {
        a += partials[i * 3 + 0];
        c += partials[i * 3 + 1];
        e += partials[i * 3 + 2];
    }
    sm0[tid] = a; sm1[tid] = c; sm2[tid] = e;
    __syncthreads();
    for (int s = 128; s > 0; s >>= 1) {
        if (tid < s) {
            sm0[tid] += sm0[tid + s];
            sm1[tid] += sm1[tid + s];
            sm2[tid] += sm2[tid + s];
        }
        __syncthreads();
    }
    if (tid == 0) {
        const double jl = sm0[0], tl = sm1[0], ac = sm2[0];
        const double total = (double)BB * (double)NN;
        out[0] = (float)((jl + 0.5 * tl) / total);  // loss
        out[1] = (float)(jl / total);               // j_mae
        out[2] = (float)(ac / total);               // type_acc
    }
}

extern "C" void kernel_launch(void* const* d_in, const int* in_sizes, int n_in,
                              void* d_out, int out_size, void* d_ws, size_t ws_size,
                              hipStream_t stream) {
    const float* pred_j       = (const float*)d_in[0];
    const float* logits       = (const float*)d_in[1];
    const float* target_j     = (const float*)d_in[2];
    const int*   target_types = (const int*)  d_in[3];

    double* partials = (double*)d_ws;   // 4096*3 doubles = 96 KB
    float*  out      = (float*)d_out;

    hungarian_lsa_kernel<<<BB, 64, 0, stream>>>(
        pred_j, logits, target_j, target_types, partials);
    hungarian_finalize_kernel<<<1, 256, 0, stream>>>(partials, out);
}

// Round 22
// 47.234 us; speedup vs baseline: 1.1184x; 1.1184x over previous
//
#include <hip/hip_runtime.h>
#include <math.h>

// HungarianLoss: B=4096 independent 32x32 degenerate-JV problems + matched loss.
// One wave per batch; lane <-> column (lanes 32-63 masked off in hot loop).
// FINAL CONFIGURATION (r20, best of 15 measured experiments):
//   kernel 39.0us / total 47.6us, absmax 0.0.
//
// Reference semantics (its _lsa_square never writes back minv/way):
//   for row i: j0=0; used={}; p[0]=i
//     loop: used+={j0}; i0=p[j0]
//           j1 = argmin_{free j}(cost[i0-1][j] - u[i0] - v[j]); delta = that min
//           u[p[used]] += delta; v[used] -= delta
//           j0=j1; if p[j0]==0 break
//     p[j0] = i   // only terminal column assigned
//
// Negative results documented on this problem (MI355X):
//  - switch-select & cndmask-tree register arrays -> LLVM re-canonicalizes to
//    alloca/scratch (r10: 55us, r11: 590us). ext_vector + uniform extract ->
//    v_movrels is the working primitive (r12).
//  - per-step latency shaves null: issue-bound, not latency-bound (r12).
//  - flat if/else walk loop: +50% (r14). Keep rotated for+while shape.
//  - inline-asm cndmask w/ "s" mask: neutral (r17/r18 bisect).
//  - in-kernel finalize: per-block __threadfence 39->89us (r18); same-address
//    atomicAdd 39->55us (r19). Tiny second kernel (~3us) wins.
//  - gfx950 does NOT skip all-inactive EXEC half-pass (r16 null).
//  - 1-problem/block + residency throttle for HW load balancing: +20% (r21).
// Floor arithmetic: 58Kcy/SIMD VALU issue measured = 4 waves x ~470 steps x
// ~15 VALU x 2cy; wall 39us = that / 62% busy (tail + chain latency).

constexpr int BB = 4096;
constexpr int NN = 32;
constexpr int TT = 8;
constexpr float ALPHA_F = 1.0f;
constexpr float BETA_F  = 0.5f;
constexpr float EPS_F   = 1e-8f;

typedef float f32x32 __attribute__((ext_vector_type(32)));

template <int CTRL, int ROW_MASK>
__device__ __forceinline__ float dpp_min(float x) {
    int t = __builtin_amdgcn_update_dpp(__float_as_int(x), __float_as_int(x),
                                        CTRL, ROW_MASK, 0xf, false);
    return fminf(x, __int_as_float(t));
}

// Min over lanes 0-31; broadcast via readlane (ignores EXEC). Bit-exact r6-r21.
__device__ __forceinline__ float wave32_min_bcast(float x) {
    x = dpp_min<0xB1,  0xf>(x); // quad_perm [1,0,3,2]  (xor 1)
    x = dpp_min<0x4E,  0xf>(x); // quad_perm [2,3,0,1]  (xor 2)
    x = dpp_min<0x124, 0xf>(x); // row_ror:4
    x = dpp_min<0x128, 0xf>(x); // row_ror:8   -> per-16-row min
    x = dpp_min<0x142, 0xa>(x); // row_bcast15 -> row 1 has 32-min
    return __int_as_float(__builtin_amdgcn_readlane(__float_as_int(x), 31));
}

__device__ __forceinline__ float readlane_f(float x, int lane) {
    return __int_as_float(__builtin_amdgcn_readlane(__float_as_int(x), lane));
}

__global__ __launch_bounds__(256) void hungarian_lsa_kernel(
    const float* __restrict__ pred_j,
    const float* __restrict__ logits,
    const float* __restrict__ target_j,
    const int*   __restrict__ target_types,
    double* __restrict__ partials)
{
    __shared__ float lgpS[4][NN * TT];   // log(softmax+eps), 1 KB/wave
    __shared__ float lgtS[4][NN * TT];   // raw logits for epilogue gather

    const int wave = threadIdx.x >> 6;
    const int lane = threadIdx.x & 63;
    const int col  = lane & 31;
    const int b    = blockIdx.x * 4 + wave;

    float* lgp = lgpS[wave];
    float* lgt = lgtS[wave];

    // ---- per-lane row data (lane r <-> row r) ----
    const float pj = pred_j  [b * NN + col];
    const float tj = target_j[b * NN + col];
    const int   tt = target_types[b * NN + col];

    float x[TT];
    const float* lrow = logits + ((size_t)b * NN + col) * TT;
#pragma unroll
    for (int t = 0; t < TT; ++t) x[t] = lrow[t];

    float m = x[0]; int am = 0;
#pragma unroll
    for (int t = 1; t < TT; ++t) { if (x[t] > m) { m = x[t]; am = t; } }
    float s = 0.f;
#pragma unroll
    for (int t = 0; t < TT; ++t) s += expf(x[t] - m);
    const float lse = m + logf(s);

    if (lane < 32) {
#pragma unroll
        for (int t = 0; t < TT; ++t) {
            float p = expf(x[t] - m) / s;
            lgp[col * TT + t] = logf(p + EPS_F);
            lgt[col * TT + t] = x[t];
        }
    }
    __syncthreads();

    int p_m1 = 0;        // 0-based row assigned to this col
    if (lane < 32) {     // EXEC upper half = 0 for the entire hot section
        // ---- cost column in a 32-wide register vector: cc[r] = cost[r][col] ----
        f32x32 cc;
#pragma unroll
        for (int r = 0; r < NN; ++r) {
            const float pjr = readlane_f(pj, r);       // row r's pred_j (uniform)
            const float lp  = lgp[r * TT + tt];        // LDS gather, pipelined
            cc[r] = ALPHA_F * fabsf(pjr - tj) + BETA_F * (-lp);
        }

        // ---- degenerate shortest-path walks (deferred duals, nvm merge) ----
        const float INFF = __builtin_inff();
        float negv = 0.f;    // -v[col+1]  (frozen during a walk)
        float ucf  = 0.f;    // u[p[col+1]] (frozen during a walk)
        unsigned amask = 0u; // assigned-column bitmask (wave-uniform)

        for (int i = 1; i <= NN; ++i) {
            float nvm   = negv;  // per-lane: -v, overwritten with INF at join
            float snap  = 0.f;   // rowSum at the moment col joined
            float curm  = cc[i - 1] + nvm;
            float mv    = wave32_min_bcast(curm);
            unsigned long long bm = __ballot(curm == mv);
            int   j1m1  = __ffsll(bm) - 1;     // argmin col (lowest on ties)
            float rowSum = mv;                 // u[i] accumulator (uniform value)

            while ((amask >> j1m1) & 1u) {     // chosen col assigned -> walk on
                const bool isJ = (col == j1m1);
                snap = isJ ? rowSum : snap;    // join: window starts here
                nvm  = isJ ? INFF   : nvm;     // join: exclude from argmin
                const float u_curV = readlane_f(ucf, j1m1);        // walk-start u
                const int   r0     = __builtin_amdgcn_readlane(p_m1, j1m1);
                curm = cc[r0] + nvm;                               // uniform idx
                mv   = wave32_min_bcast(curm);
                bm   = __ballot(curm == mv);
                j1m1 = __ffsll(bm) - 1;
                rowSum += mv - u_curV;
            }

            // terminal: assign row i to column j1; apply deferred duals
            const bool isJ = (col == j1m1);
            p_m1 = isJ ? (i - 1) : p_m1;
            const float dv  = rowSum - snap;             // deltas since join
            const float dvj = (nvm == INFF) ? dv : 0.f;  // joined lanes only
            negv += dvj;                                 // v[used] -= dv
            ucf  += dvj;                                 // u[p[used]] += dv
            ucf   = isJ ? rowSum : ucf;                  // u[i] -> terminal col
            amask |= 1u << j1m1;
        }
    }

    // ---- matched loss contributions (column-centric; bijection == row sum) ----
    const int   row      = p_m1;                 // upper lanes: 0 (masked below)
    const float pj_row   = __shfl(pj,  row);
    const float lse_row  = __shfl(lse, row);
    const int   am_row   = __shfl(am,  row);
    const float logit_tt = lgt[row * TT + tt];

    double sj = (lane < 32) ? (double)fabsf(pj_row - tj)   : 0.0;
    double st = (lane < 32) ? (double)(lse_row - logit_tt) : 0.0;
    double sa = (lane < 32) ? ((am_row == tt) ? 1.0 : 0.0) : 0.0;
#pragma unroll
    for (int off = 32; off >= 1; off >>= 1) {
        sj += __shfl_xor(sj, off);
        st += __shfl_xor(st, off);
        sa += __shfl_xor(sa, off);
    }
    if (lane == 0) {
        partials[b * 3 + 0] = sj;
        partials[b * 3 + 1] = st;
        partials[b * 3 + 2] = sa;
    }
}

__global__ __launch_bounds__(256) void hungarian_finalize_kernel(
    const double* __restrict__ partials, float* __restrict__ out)
{
    __shared__ double sm0[256], sm1[256], sm2[256];
    const int tid = threadIdx.x;
    double a = 0.0, c = 0.0, e = 0.0;
    for (int i = tid; i < BB; i += 256) {
        a += partials[i * 3 + 0];
        c += partials[i * 3 + 1];
        e += partials[i * 3 + 2];
    }
    sm0[tid] = a; sm1[tid] = c; sm2[tid] = e;
    __syncthreads();
    for (int s = 128; s > 0; s >>= 1) {
        if (tid < s) {
            sm0[tid] += sm0[tid + s];
            sm1[tid] += sm1[tid + s];
            sm2[tid] += sm2[tid + s];
        }
        __syncthreads();
    }
    if (tid == 0) {
        const double jl = sm0[0], tl = sm1[0], ac = sm2[0];
        const double total = (double)BB * (double)NN;
        out[0] = (float)((jl + 0.5 * tl) / total);  // loss
        out[1] = (float)(jl / total);               // j_mae
        out[2] = (float)(ac / total);               // type_acc
    }
}

extern "C" void kernel_launch(void* const* d_in, const int* in_sizes, int n_in,
                              void* d_out, int out_size, void* d_ws, size_t ws_size,
                              hipStream_t stream) {
    const float* pred_j       = (const float*)d_in[0];
    const float* logits       = (const float*)d_in[1];
    const float* target_j     = (const float*)d_in[2];
    const int*   target_types = (const int*)  d_in[3];

    double* partials = (double*)d_ws;   // 4096*3 doubles = 96 KB
    float*  out      = (float*)d_out;

    hungarian_lsa_kernel<<<BB / 4, 256, 0, stream>>>(
        pred_j, logits, target_j, target_types, partials);
    hungarian_finalize_kernel<<<1, 256, 0, stream>>>(partials, out);
}